// Round 3
// baseline (177.007 us; speedup 1.0000x reference)
//
#include <hip/hip_runtime.h>
#include <math.h>

// out[b,c] = tanh( sum_{hw} x[b,c,h,w] * W[c,h,w] + bias[c] )
// x: [B=4096, C=512, 7, 7] f32; each (b,c) row = 49 contiguous floats.
//
// R3 design: barrier-free software pipeline (T14 async-stage split).
//  - 64-thread (1-wave) blocks; 64-row tile = 12544 B LDS (~12 blocks/CU).
//  - Per tile: issue next tile's loads to regs -> compute current tile from
//    LDS -> reg->LDS write (counted vmcnt, no vmcnt(0) drain, no s_barrier).
//  - Same-wave DS ops are FIFO => cross-lane LDS visibility without barriers;
//    lgkmcnt(0) fence + "memory" clobber pins the compiler.
//  - W row + bias hoisted to registers (global W loads would poison the
//    FIFO-counted vmcnt pipeline).

constexpr int K    = 49;     // 7*7
constexpr int TPB  = 64;     // 1 wave per block
constexpr int GRID = 3328;   // multiple of 8 => c invariant per block

__global__ __launch_bounds__(64) void WGP_84018150245011_kernel(
    const float* __restrict__ x,
    const float* __restrict__ W,
    const float* __restrict__ bias,
    float* __restrict__ out,
    int n_tiles) {
  __shared__ float xs[TPB * K];  // 12544 B

  const int lane = threadIdx.x;

  // tile t handled by this block has t % 8 == blockIdx.x % 8 (GRID % 8 == 0),
  // so channel c = (t*64 + lane) % 512 = ((bid&7)<<6) | lane is loop-invariant.
  const int c = ((blockIdx.x & 7) << 6) | lane;

  float w[K];
  const float* __restrict__ wr = W + c * K;
#pragma unroll
  for (int k = 0; k < K; ++k) w[k] = wr[k];
  const float bi = bias[c];

  float4* dst4 = reinterpret_cast<float4*>(xs);

  float4 p[12];   // prefetch registers: 12 float4 + 1 tail float per lane
  float  ptail;

  int t = blockIdx.x;

  // ---- prologue: load tile t to regs, spill to LDS ----
  {
    const float4* __restrict__ src4 =
        reinterpret_cast<const float4*>(x) + (size_t)t * (TPB * K / 4);
#pragma unroll
    for (int j = 0; j < 12; ++j) p[j] = src4[lane + j * 64];
    ptail = x[(size_t)t * (TPB * K) + 3072 + lane];
#pragma unroll
    for (int j = 0; j < 12; ++j) dst4[lane + j * 64] = p[j];
    xs[3072 + lane] = ptail;
    asm volatile("s_waitcnt lgkmcnt(0)" ::: "memory");
  }

#pragma unroll 1
  for (; t < n_tiles;) {
    const int tn = t + GRID;
    const bool more = (tn < n_tiles);

    // 1. issue next tile's global loads (oldest in vmcnt FIFO)
    if (more) {
      const float4* __restrict__ src4 =
          reinterpret_cast<const float4*>(x) + (size_t)tn * (TPB * K / 4);
#pragma unroll
      for (int j = 0; j < 12; ++j) p[j] = src4[lane + j * 64];
      ptail = x[(size_t)tn * (TPB * K) + 3072 + lane];
    }

    // 2. compute current tile from LDS (row stride 49 -> bank stride 17, ~free)
    {
      const float* xr = xs + lane * K;
      float s = bi;
#pragma unroll
      for (int k = 0; k < K; ++k) s = fmaf(xr[k], w[k], s);
      out[(size_t)t * TPB + lane] = tanhf(s);
    }

    // 3. reg -> LDS for next tile (compiler inserts counted vmcnt for p[]);
    //    same-wave DS FIFO orders these after step-2 ds_reads.
    if (more) {
#pragma unroll
      for (int j = 0; j < 12; ++j) dst4[lane + j * 64] = p[j];
      xs[3072 + lane] = ptail;
      asm volatile("s_waitcnt lgkmcnt(0)" ::: "memory");
    }
    t = tn;
  }
}

extern "C" void kernel_launch(void* const* d_in, const int* in_sizes, int n_in,
                              void* d_out, int out_size, void* d_ws, size_t ws_size,
                              hipStream_t stream) {
  const float* x    = (const float*)d_in[0];
  const float* W    = (const float*)d_in[1];
  const float* bias = (const float*)d_in[2];
  float* out        = (float*)d_out;

  const int n_rows  = in_sizes[0] / K;   // B*C = 2,097,152
  const int n_tiles = n_rows / TPB;      // 32768 (exact)

  WGP_84018150245011_kernel<<<GRID, TPB, 0, stream>>>(x, W, bias, out, n_tiles);
}

// Round 4
// 84.885 us; speedup vs baseline: 2.0853x; 2.0853x over previous
//
#include <hip/hip_runtime.h>
#include <math.h>

// out[b,c] = tanh( sum_{hw} x[b,c,h,w] * W[c,h,w] + bias[c] )
// x: [B=4096, C=512, 7, 7] f32; each (b,c) row = 49 contiguous floats.
//
// R4 design: barrier-free async-DMA pipeline.
//  - 1-wave (64-thread) blocks; 64-row tile = 12544 B; double-buffered LDS
//    (25088 B/block -> 6 blocks/CU).
//  - Stage via __builtin_amdgcn_global_load_lds width=16 (no VGPR round-trip):
//    12 x 16B/lane + 1 x 4B/lane tail = 13 DMA issues per tile.
//  - Counted s_waitcnt vmcnt(13): waits only for the PREVIOUS tile's loads
//    (issued one full iteration earlier); next tile's 13 loads stay in flight
//    across the compute. No __syncthreads anywhere (1 wave/block).
//  - W row + bias hoisted to registers (GRID % 8 == 0 => c loop-invariant).

constexpr int K    = 49;        // 7*7
constexpr int TPB  = 64;        // 1 wave per block
constexpr int TILE = TPB * K;   // 3136 floats = 12544 B
constexpr int GRID = 2048;      // 32768 tiles / 2048 = 16 iters, GRID%8==0

__global__ __launch_bounds__(64) void WGP_84018150245011_kernel(
    const float* __restrict__ x,
    const float* __restrict__ W,
    const float* __restrict__ bias,
    float* __restrict__ out,
    int iters) {
  __shared__ float xs[2][TILE];

  const int lane = threadIdx.x;

  // tile t of this block: t % 8 == blockIdx.x % 8, so c = (t*64+lane) % 512
  // = ((bid&7)<<6)|lane is loop-invariant.
  const int c = ((blockIdx.x & 7) << 6) | lane;

  float w[K];
  const float* __restrict__ wr = W + c * K;
#pragma unroll
  for (int k = 0; k < K; ++k) w[k] = wr[k];
  const float bi = bias[c];

  // Async-stage one tile into xs[buf]: LDS dest is wave-uniform base
  // (+ lane*size implicit); global src is per-lane.
  auto stage = [&](int t, int buf) {
    const float* src = x + (size_t)t * TILE;
#pragma unroll
    for (int j = 0; j < 12; ++j) {
      __builtin_amdgcn_global_load_lds(
          (const __attribute__((address_space(1))) unsigned int*)(src + j * 256 + lane * 4),
          (__attribute__((address_space(3))) unsigned int*)(&xs[buf][j * 256]),
          16, 0, 0);
    }
    __builtin_amdgcn_global_load_lds(
        (const __attribute__((address_space(1))) unsigned int*)(src + 3072 + lane),
        (__attribute__((address_space(3))) unsigned int*)(&xs[buf][3072]),
        4, 0, 0);
  };

  // Reduce row `lane` of xs[buf] against registered W; write out[t*64+lane].
  auto compute = [&](int buf, int t) {
    const float* xr = &xs[buf][lane * K];  // stride 49 floats -> bank stride 17, conflict-free
    float s = bi;
#pragma unroll
    for (int k = 0; k < K; ++k) s = fmaf(xr[k], w[k], s);
    out[(size_t)t * TPB + lane] = tanhf(s);
  };

  int t   = blockIdx.x;
  int buf = 0;
  stage(t, 0);  // prologue: 13 loads in flight

#pragma unroll 1
  for (int i = 1; i < iters; ++i) {
    const int tn = t + GRID;
    stage(tn, buf ^ 1);                               // +13 issues (27 max w/ store)
    asm volatile("s_waitcnt vmcnt(13)" ::: "memory"); // prev tile's 13 done; next 13 in flight
    compute(buf, t);
    buf ^= 1;
    t = tn;
  }
  asm volatile("s_waitcnt vmcnt(0)" ::: "memory");    // epilogue drain
  compute(buf, t);
}

extern "C" void kernel_launch(void* const* d_in, const int* in_sizes, int n_in,
                              void* d_out, int out_size, void* d_ws, size_t ws_size,
                              hipStream_t stream) {
  const float* x    = (const float*)d_in[0];
  const float* W    = (const float*)d_in[1];
  const float* bias = (const float*)d_in[2];
  float* out        = (float*)d_out;

  const int n_rows  = in_sizes[0] / K;   // B*C = 2,097,152
  const int n_tiles = n_rows / TPB;      // 32768
  const int iters   = n_tiles / GRID;    // 16 (exact)

  WGP_84018150245011_kernel<<<GRID, TPB, 0, stream>>>(x, W, bias, out, iters);
}

// Round 5
// 74.000 us; speedup vs baseline: 2.3920x; 1.1471x over previous
//
#include <hip/hip_runtime.h>
#include <math.h>

// out[b,c] = tanh( sum_{hw} x[b,c,h,w] * W[c,h,w] + bias[c] )
// x: [B=4096, C=512, 7, 7] f32; each (b,c) row = 49 contiguous floats.
//
// R5 = R2 structure (best: 83.35 us) with ONE change: x staging loads are
// NON-TEMPORAL (nt cache policy). x is 411 MB read-once streaming data;
// theory is the ~5.0 TB/s plateau (vs 6.3-6.8 on copy/fill) is L2/L3
// line-allocation churn, which nt bypasses.

constexpr int K    = 49;   // 7*7
constexpr int ROWS = 256;  // rows per tile == threads per block
constexpr int GRID = 2048; // EVEN => tile parity (g%2) constant per block

typedef float f32x4 __attribute__((ext_vector_type(4)));

__global__ __launch_bounds__(256) void WGP_84018150245011_kernel(
    const float* __restrict__ x,
    const float* __restrict__ W,
    const float* __restrict__ bias,
    float* __restrict__ out,
    int n_tiles) {
  __shared__ float xs[ROWS * K];  // 50176 B; stride-49 reads -> bank stride 17, conflict-free

  const int tid = threadIdx.x;

  // c = (g%2)*256 + tid, g%2 == blockIdx.x%2 (GRID even) => loop-invariant.
  const int c = ((blockIdx.x & 1) << 8) | tid;

  float w[K];
  const float* __restrict__ wr = W + c * K;
#pragma unroll
  for (int k = 0; k < K; ++k) w[k] = wr[k];
  const float bi = bias[c];

  for (int g = blockIdx.x; g < n_tiles; g += GRID) {
    // ---- Stage: 3136 float4, block-contiguous, 16B-aligned, NON-TEMPORAL ----
    const f32x4* __restrict__ src4 =
        reinterpret_cast<const f32x4*>(x) + (size_t)g * (ROWS * K / 4);
    f32x4* dst4 = reinterpret_cast<f32x4*>(xs);
#pragma unroll
    for (int j = 0; j < 12; ++j) {          // 12*256 = 3072 float4
      dst4[tid + j * 256] = __builtin_nontemporal_load(&src4[tid + j * 256]);
    }
    if (tid < 64) {                         // remaining 64 float4
      dst4[tid + 3072] = __builtin_nontemporal_load(&src4[tid + 3072]);
    }
    __syncthreads();

    // ---- Reduce: thread t owns row t of this tile ----
    const float* xr = xs + tid * K;
    float s = bi;
#pragma unroll
    for (int k = 0; k < K; ++k) {
      s = fmaf(xr[k], w[k], s);
    }
    out[(size_t)g * ROWS + tid] = tanhf(s);
    __syncthreads();  // WAR guard before next tile's stage
  }
}

extern "C" void kernel_launch(void* const* d_in, const int* in_sizes, int n_in,
                              void* d_out, int out_size, void* d_ws, size_t ws_size,
                              hipStream_t stream) {
  const float* x    = (const float*)d_in[0];
  const float* W    = (const float*)d_in[1];
  const float* bias = (const float*)d_in[2];
  float* out        = (float*)d_out;

  const int n_rows  = in_sizes[0] / K;       // B*C = 2,097,152
  const int n_tiles = n_rows / ROWS;         // 8192 (exact)

  WGP_84018150245011_kernel<<<GRID, ROWS, 0, stream>>>(x, W, bias, out, n_tiles);
}